// Round 15
// baseline (105.321 us; speedup 1.0000x reference)
//
#include <hip/hip_runtime.h>

// ---------------------------------------------------------------------------
// VisualContrastiveLoss on MI355X
// loss = C + mean_i log(Z_i) - mean_i sim[i, lab_i],  C = 1/0.07
//   Z_i = sum_j exp(sim_ij - C)  (fixed shift: dots bounded by 1)
//   sim = (f f^T)/0.07, f = row-normalized visual_feat
// R15: barrier-free K-loop via PRIVATE per-wave B slabs.
//     Tile = 64 rows x 256 cols, 4 waves side by side (64x64 each): each
//     wave's B slab (64 rows) is private -> staged into a private 8KB LDS
//     plane with a wave-local s_waitcnt vmcnt(0) (0x0f70), NO __syncthreads
//     in the J/kk loops (the R6..R14 2-barrier-per-kk structure lockstepped
//     all 8 waves at every chunk -- the m97 plateau). A (64 x K, 32KB)
//     staged once, ONE barrier per kernel. Symmetry at 64-col granularity:
//     wave computes slab only if slabCol>=I; col-sum transpose atomics when
//     strictly above; diag slab -> D. Balance: grid (64,16), I=bx / 127-bx
//     pairing (R14). LDS 64KB -> 2 blocks/CU. Kept: h() zero-conflict
//     granule layout, FragU b128 frag loads, raw v_exp_f32, unroll-1,
//     3-kernel structure (fused-tail fence cost ~37us, R10; the ~45us
//     fillBuffer workspace poison is harness-owned and untouchable).
// ---------------------------------------------------------------------------

typedef int i32x8 __attribute__((ext_vector_type(8)));
typedef float f32x4 __attribute__((ext_vector_type(4)));

#define B_N 8192
#define D_K 512
#define ROWB 512  // bytes per fp8 row
#define INVT 14.285714285714286f
// (1/0.07) * log2(e)
#define SCALE_LOG2 20.609929155556622f

#if defined(__has_builtin) && __has_builtin(__builtin_amdgcn_exp2f)
#define FAST_EXP2(x) __builtin_amdgcn_exp2f(x)
#else
#define FAST_EXP2(x) exp2f(x)
#endif

union FragU {
  int4 h[2];
  i32x8 v;
};

static __device__ __forceinline__ void load16_to_lds(const void* g, void* l) {
  __builtin_amdgcn_global_load_lds(
      (const __attribute__((address_space(1))) unsigned int*)g,
      (__attribute__((address_space(3))) unsigned int*)l, 16, 0, 0);
}

// ---- K1: 4 waves/block, one wave per row; normalize fp32 -> fp8 e4m3 --------
// Also zeroes Z (ws is poisoned before every launch).
__global__ __launch_bounds__(256)
void norm_kernel(const float* __restrict__ x,
                 unsigned char* __restrict__ fQ,
                 float* __restrict__ Z) {
  const int row = blockIdx.x * 4 + (threadIdx.x >> 6);
  const int lane = threadIdx.x & 63;
  const float4* xr = (const float4*)(x + (size_t)row * D_K);
  float4 a = xr[2 * lane];
  float4 b = xr[2 * lane + 1];
  float s = a.x * a.x + a.y * a.y + a.z * a.z + a.w * a.w +
            b.x * b.x + b.y * b.y + b.z * b.z + b.w * b.w;
#pragma unroll
  for (int off = 1; off < 64; off <<= 1) s += __shfl_xor(s, off);
  const float inv = 1.0f / fmaxf(sqrtf(s), 1e-12f);
  int lo = 0, hi = 0;
  lo = __builtin_amdgcn_cvt_pk_fp8_f32(a.x * inv, a.y * inv, lo, false);
  lo = __builtin_amdgcn_cvt_pk_fp8_f32(a.z * inv, a.w * inv, lo, true);
  hi = __builtin_amdgcn_cvt_pk_fp8_f32(b.x * inv, b.y * inv, hi, false);
  hi = __builtin_amdgcn_cvt_pk_fp8_f32(b.z * inv, b.w * inv, hi, true);
  int2 p; p.x = lo; p.y = hi;
  ((int2*)(fQ + (size_t)row * ROWB))[lane] = p;
  if (lane == 0) Z[row] = 0.0f;
}

// ---- K2: upper-triangular fp8 similarity, barrier-free K-loop ---------------
// grid (64, 16): by<8 -> I=bx, by>=8 -> I=127-bx (64-row bands, R14 pairing).
// Tile = 64 rows x 256 cols; wave w owns cols Jg*256 + w*64 (private slab).
// Wave computes slab iff slabCol=4*Jg+w >= I. Jg walks class (by&7) mod 8
// from Jmin=I>>2. A staged once (4 chunk-planes, h() granule swizzle);
// B staged per kk into the wave's PRIVATE 8KB plane; wave-local
// s_waitcnt vmcnt(0); no __syncthreads after the A barrier.
__global__ __launch_bounds__(256, 2)
void sim_kernel(const unsigned char* __restrict__ fQ,
                float* __restrict__ Z, float* __restrict__ T01,
                float* __restrict__ D) {
  __shared__ unsigned char ldsA[4][64 * 128];  // 32 KB: full K, 4 chunk-planes
  __shared__ unsigned char ldsB[4][64 * 128];  // 32 KB: private 8KB per wave

  const int tid = threadIdx.x;
  const int lane = tid & 63;
  const int w = tid >> 6;
  const int bx = blockIdx.x, by = blockIdx.y;
  const int I = (by < 8) ? bx : (127 - bx);   // 64-row band index
  const int c = by & 7;                        // Jg class mod 8
  const int Jmin = I >> 2;
  const int Jfirst = Jmin + ((c - Jmin) & 7);
  if (Jfirst > 31) return;                     // uniform per block
  const int I0 = I * 64;

  // staging lane geometry: 8 rows x 8 slots(16B) per instruction.
  // slot b of row a sources global granule h(b^a), h(u)=2(u&3)+(u>>2).
  const int srow = lane >> 3;                 // 0..7
  const int sb = lane & 7;                    // dest slot
  const int su = sb ^ srow;
  const int sg = 2 * (su & 3) + (su >> 2);    // source granule
  const size_t sOff = (size_t)srow * ROWB + sg * 16;  // bytes

  // fragment-read lane geometry
  const int fr = lane & 15;   // M/N index within 16
  const int q = lane >> 4;    // quad -> k chunk of 32B
  const int swz = fr & 7;     // row&7 of the frag row
  const int off0 = (q ^ swz) * 16;        // slot holding granule 2q
  const int off1 = ((q + 4) ^ swz) * 16;  // slot holding granule 2q+1

  // ---- stage A once: wave w stages rows w*16..+15 of each K-chunk ----------
#pragma unroll
  for (int kk = 0; kk < 4; ++kk) {
    const unsigned char* gA = fQ + (size_t)(I0 + w * 16) * ROWB + kk * 128 + sOff;
    unsigned char* lA = ldsA[kk] + (w * 16) * 128;
#pragma unroll
    for (int rr = 0; rr < 16; rr += 8)
      load16_to_lds(gA + (size_t)rr * ROWB, lA + rr * 128);
  }
  __syncthreads();  // the ONLY barrier in this kernel

  unsigned char* myB = ldsB[w];                  // private 8 KB plane
  const unsigned char* rbBase = myB + fr * 128;  // frag row base (B slab row fr+n*16)
  const int raRow = fr * 128;

  float Zp[4][4];
#pragma unroll
  for (int m = 0; m < 4; ++m)
#pragma unroll
    for (int r = 0; r < 4; ++r) Zp[m][r] = 0.0f;

#pragma unroll 1
  for (int Jg = Jfirst; Jg < 32; Jg += 8) {
    const int slabCol = 4 * Jg + w;   // this wave's 64-col slab index
    if (slabCol < I) continue;        // lower triangle: transpose partner covers
    const int J0 = slabCol * 64;      // global col base

    f32x4 acc[4][4];
#pragma unroll
    for (int m = 0; m < 4; ++m)
#pragma unroll
      for (int n = 0; n < 4; ++n) acc[m][n] = (f32x4){0.f, 0.f, 0.f, 0.f};

#pragma unroll 1
    for (int kk = 0; kk < 4; ++kk) {
      const int k0 = kk * 128;  // byte offset into row
      {  // stage this wave's 64 B rows (private plane, 8 instrs)
        const unsigned char* gB = fQ + (size_t)J0 * ROWB + k0 + sOff;
#pragma unroll
        for (int rr = 0; rr < 64; rr += 8)
          load16_to_lds(gB + (size_t)rr * ROWB, myB + rr * 128);
      }
      __builtin_amdgcn_s_waitcnt(0x0f70);  // vmcnt(0), wave-local; no barrier

      const unsigned char* raBase = ldsA[kk] + raRow;
      i32x8 bv[4];
#pragma unroll
      for (int n = 0; n < 4; ++n) {
        const unsigned char* rb = rbBase + n * 16 * 128;
        FragU u;
        u.h[0] = *(const int4*)(rb + off0);
        u.h[1] = *(const int4*)(rb + off1);
        bv[n] = u.v;
      }
#pragma unroll
      for (int mh = 0; mh < 2; ++mh) {  // m-split: av[2] live, not av[4]
        i32x8 av[2];
#pragma unroll
        for (int m = 0; m < 2; ++m) {
          const unsigned char* ra = raBase + (mh * 2 + m) * 16 * 128;
          FragU u;
          u.h[0] = *(const int4*)(ra + off0);
          u.h[1] = *(const int4*)(ra + off1);
          av[m] = u.v;
        }
#pragma unroll
        for (int m = 0; m < 2; ++m)
#pragma unroll
          for (int n = 0; n < 4; ++n)
            acc[mh * 2 + m][n] = __builtin_amdgcn_mfma_scale_f32_16x16x128_f8f6f4(
                av[m], bv[n], acc[mh * 2 + m][n], 0, 0, 0, 127, 0, 127);
      }
    }

    // T01: sim[0,c], sim[1,c] (band I==0; rows 0,1 = frag m=0, q==0, r=0,1)
    if (I == 0 && q == 0) {
#pragma unroll
      for (int n = 0; n < 4; ++n) {
        const int col = J0 + n * 16 + fr;
        T01[col * 2 + 0] = acc[0][n][0] * INVT;
        T01[col * 2 + 1] = acc[0][n][1] * INVT;
      }
    }

    // D: diagonal slab only (slabCol == I): row==col elements
    if (slabCol == I) {
#pragma unroll
      for (int m = 0; m < 4; ++m)
#pragma unroll
        for (int n = 0; n < 4; ++n) {
          const int colL = n * 16 + fr;
#pragma unroll
          for (int r = 0; r < 4; ++r) {
            const int rowL = m * 16 + q * 4 + r;
            if (rowL == colL) D[I0 + rowL] = acc[m][n][r];
          }
        }
    }

    // Z: row partials always; column sums (transpose) for strictly-above slabs
    const bool offd = (slabCol != I);
#pragma unroll
    for (int n = 0; n < 4; ++n) {
      float cs = 0.0f;
#pragma unroll
      for (int m = 0; m < 4; ++m)
#pragma unroll
        for (int r = 0; r < 4; ++r) {
          const float e = FAST_EXP2((acc[m][n][r] - 1.0f) * SCALE_LOG2);
          Zp[m][r] += e;
          cs += e;
        }
      if (offd) {
        cs += __shfl_xor(cs, 16);
        cs += __shfl_xor(cs, 32);
        if (q == 0) atomicAdd(&Z[J0 + n * 16 + fr], cs);
      }
    }
  }

  // row sums: reduce Zp across the 16 col-lanes, then atomicAdd
#pragma unroll
  for (int m = 0; m < 4; ++m)
#pragma unroll
    for (int r = 0; r < 4; ++r) {
      float v = Zp[m][r];
      v += __shfl_xor(v, 1);
      v += __shfl_xor(v, 2);
      v += __shfl_xor(v, 4);
      v += __shfl_xor(v, 8);
      if (fr == 0) atomicAdd(&Z[I0 + m * 16 + q * 4 + r], v);
    }
}

// ---- K3: labels + exact-diagonal fixup + final loss reduction ---------------
// 1024 threads, 8 rows each, all loads batched/independent.
__global__ __launch_bounds__(1024)
void finalize_kernel(const float* __restrict__ Z,
                     const float* __restrict__ T01,
                     const float* __restrict__ D,
                     const int* __restrict__ ids,
                     const int* __restrict__ anchor,
                     float* __restrict__ out) {
  __shared__ float red[1024];
  const int t = threadIdx.x;
  const int anchor_id = ids[anchor[0]];
  const int sameLast = (ids[B_N - 1] == anchor_id);
  const int samePrev = (ids[B_N - 2] == anchor_id);
  int i[8], id[8];
  float z[8], d[8], t0[8], t1[8];
#pragma unroll
  for (int u = 0; u < 8; ++u) {
    i[u] = u * 1024 + t;
    z[u] = Z[i[u]];
    d[u] = D[i[u]];
    t0[u] = T01[i[u] * 2 + 0];
    t1[u] = T01[i[u] * 2 + 1];
    id[u] = ids[i[u]];
  }
  float sum = 0.0f;
#pragma unroll
  for (int u = 0; u < 8; ++u) {
    const int same_i = (id[u] == anchor_id);
    const int lab =
        (i[u] < B_N - 1) ? (same_i & sameLast) : (sameLast & samePrev);
    const float tt = lab ? t1[u] : t0[u];
    // replace quantized diag contribution with the exact value exp(0)=1
    const float Zc = z[u] - FAST_EXP2((d[u] - 1.0f) * SCALE_LOG2) + 1.0f;
    sum += tt - (INVT + logf(Zc));
  }
  red[t] = sum;
  __syncthreads();
  for (int off = 512; off > 0; off >>= 1) {
    if (t < off) red[t] += red[t + off];
    __syncthreads();
  }
  if (t == 0) out[0] = -red[0] / (float)B_N;
}

// ---------------------------------------------------------------------------
extern "C" void kernel_launch(void* const* d_in, const int* in_sizes, int n_in,
                              void* d_out, int out_size, void* d_ws, size_t ws_size,
                              hipStream_t stream) {
  const float* x = (const float*)d_in[0];
  const int* ids = (const int*)d_in[1];
  const int* anchor = (const int*)d_in[2];
  float* out = (float*)d_out;

  unsigned char* fQ = (unsigned char*)d_ws;                    // 4 MB fp8
  float* Z = (float*)((char*)d_ws + (size_t)B_N * ROWB);       // 32 KB
  float* T01 = Z + B_N;                                        // 64 KB
  float* D = T01 + 2 * B_N;                                    // 32 KB

  norm_kernel<<<B_N / 4, 256, 0, stream>>>(x, fQ, Z);
  sim_kernel<<<dim3(64, 16), 256, 0, stream>>>(fQ, Z, T01, D);
  finalize_kernel<<<1, 1024, 0, stream>>>(Z, T01, D, ids, anchor, out);
}

// Round 16
// 104.600 us; speedup vs baseline: 1.0069x; 1.0069x over previous
//
#include <hip/hip_runtime.h>

// ---------------------------------------------------------------------------
// VisualContrastiveLoss on MI355X
// loss = C + mean_i log(Z_i) - mean_i sim[i, lab_i],  C = 1/0.07
//   Z_i = sum_j exp(sim_ij - C)  (fixed shift: dots bounded by 1)
//   sim = (f f^T)/0.07, f = row-normalized visual_feat
// R16: R14 sim (best, 104.4us total) kept BIT-IDENTICAL; safe wins outside:
//     (a) finalize: raw v_log_f32 (ln(x)=ln2*log2(x)) -- logf without
//         -ffast-math is the ocml wrapper, same waste class as R13's exp2f.
//     (b) norm: 2 rows/wave -> 2 independent load/reduce chains (norm was
//         ~2x its 3.2us HBM floor on a single dependent chain).
//     Ledger: fill 45us (harness, untouchable) + restore ~5 + norm + sim ~34
//     + finalize + gaps. R12/R15 both showed sim's K-loop restructures are
//     neutral vs R14's 2-barrier form at 4 waves/SIMD.
// ---------------------------------------------------------------------------

typedef int i32x8 __attribute__((ext_vector_type(8)));
typedef float f32x4 __attribute__((ext_vector_type(4)));

#define B_N 8192
#define D_K 512
#define ROWB 512  // bytes per fp8 row
#define INVT 14.285714285714286f
// (1/0.07) * log2(e)
#define SCALE_LOG2 20.609929155556622f
#define LN2F 0.6931471805599453f

#if defined(__has_builtin) && __has_builtin(__builtin_amdgcn_exp2f)
#define FAST_EXP2(x) __builtin_amdgcn_exp2f(x)
#else
#define FAST_EXP2(x) exp2f(x)
#endif

#if defined(__has_builtin) && __has_builtin(__builtin_amdgcn_logf)
#define FAST_LN(x) (LN2F * __builtin_amdgcn_logf(x))
#else
#define FAST_LN(x) logf(x)
#endif

union FragU {
  int4 h[2];
  i32x8 v;
};

static __device__ __forceinline__ void load16_to_lds(const void* g, void* l) {
  __builtin_amdgcn_global_load_lds(
      (const __attribute__((address_space(1))) unsigned int*)g,
      (__attribute__((address_space(3))) unsigned int*)l, 16, 0, 0);
}

// ---- K1: 4 waves/block, TWO rows per wave; normalize fp32 -> fp8 e4m3 -------
// Two independent load/reduce chains per wave double memory-level parallelism.
// Also zeroes Z (ws is poisoned before every launch).
__global__ __launch_bounds__(256)
void norm_kernel(const float* __restrict__ x,
                 unsigned char* __restrict__ fQ,
                 float* __restrict__ Z) {
  const int wv = threadIdx.x >> 6;
  const int lane = threadIdx.x & 63;
  const int row0 = blockIdx.x * 8 + wv * 2;
  const float4* xr0 = (const float4*)(x + (size_t)row0 * D_K);
  const float4* xr1 = (const float4*)(x + (size_t)(row0 + 1) * D_K);
  float4 a0 = xr0[2 * lane], b0 = xr0[2 * lane + 1];
  float4 a1 = xr1[2 * lane], b1 = xr1[2 * lane + 1];
  float s0 = a0.x * a0.x + a0.y * a0.y + a0.z * a0.z + a0.w * a0.w +
             b0.x * b0.x + b0.y * b0.y + b0.z * b0.z + b0.w * b0.w;
  float s1 = a1.x * a1.x + a1.y * a1.y + a1.z * a1.z + a1.w * a1.w +
             b1.x * b1.x + b1.y * b1.y + b1.z * b1.z + b1.w * b1.w;
#pragma unroll
  for (int off = 1; off < 64; off <<= 1) {
    s0 += __shfl_xor(s0, off);
    s1 += __shfl_xor(s1, off);
  }
  const float inv0 = 1.0f / fmaxf(sqrtf(s0), 1e-12f);
  const float inv1 = 1.0f / fmaxf(sqrtf(s1), 1e-12f);
  int lo0 = 0, hi0 = 0, lo1 = 0, hi1 = 0;
  lo0 = __builtin_amdgcn_cvt_pk_fp8_f32(a0.x * inv0, a0.y * inv0, lo0, false);
  lo0 = __builtin_amdgcn_cvt_pk_fp8_f32(a0.z * inv0, a0.w * inv0, lo0, true);
  hi0 = __builtin_amdgcn_cvt_pk_fp8_f32(b0.x * inv0, b0.y * inv0, hi0, false);
  hi0 = __builtin_amdgcn_cvt_pk_fp8_f32(b0.z * inv0, b0.w * inv0, hi0, true);
  lo1 = __builtin_amdgcn_cvt_pk_fp8_f32(a1.x * inv1, a1.y * inv1, lo1, false);
  lo1 = __builtin_amdgcn_cvt_pk_fp8_f32(a1.z * inv1, a1.w * inv1, lo1, true);
  hi1 = __builtin_amdgcn_cvt_pk_fp8_f32(b1.x * inv1, b1.y * inv1, hi1, false);
  hi1 = __builtin_amdgcn_cvt_pk_fp8_f32(b1.z * inv1, b1.w * inv1, hi1, true);
  int2 p0; p0.x = lo0; p0.y = hi0;
  int2 p1; p1.x = lo1; p1.y = hi1;
  ((int2*)(fQ + (size_t)row0 * ROWB))[lane] = p0;
  ((int2*)(fQ + (size_t)(row0 + 1) * ROWB))[lane] = p1;
  if (lane == 0) {
    Z[row0] = 0.0f;
    Z[row0 + 1] = 0.0f;
  }
}

// ---- K2: upper-triangular fp8 similarity + softmax-denominator --------------
// (bit-identical to R14) grid (32, 16): by<8 -> I=bx; by>=8 -> I=63-bx.
// Tile cols J in {J >= I, J == (by&7) mod 8}. 4 waves 2x2; wave owns 64x64 C
// via 4x4 frags of 16x16x128 MX-fp8 MFMA (scale=1). A staged once (4 chunk-
// planes, h() zero-conflict granule layout); B staged per kk.
__global__ __launch_bounds__(256, 2)
void sim_kernel(const unsigned char* __restrict__ fQ,
                float* __restrict__ Z, float* __restrict__ T01,
                float* __restrict__ D) {
  __shared__ unsigned char ldsA[4][128 * 128];  // 64 KB: full K, 4 chunk-planes
  __shared__ unsigned char ldsB[128 * 128];     // 16 KB

  const int tid = threadIdx.x;
  const int lane = tid & 63;
  const int w = tid >> 6;
  const int wm = w & 1;       // wave row strip (0/1) -> rows wm*64..
  const int wn = w >> 1;      // wave col strip (0/1) -> cols wn*64..
  const int bx = blockIdx.x, by = blockIdx.y;
  const int b = by & 7;
  const int I = (by < 8) ? bx : (63 - bx);    // row band index
  const int Jfirst = I + ((b - I) & 7);       // first J >= I with J==b (mod 8)
  if (Jfirst > 63) return;                    // no tiles for this block
  const int I0 = I * 128;

  // staging lane geometry: 8 rows x 8 slots(16B) per instruction.
  const int srow = lane >> 3;                 // 0..7
  const int sb = lane & 7;                    // dest slot
  const int su = sb ^ srow;
  const int sg = 2 * (su & 3) + (su >> 2);    // source granule
  const size_t sOff = (size_t)srow * ROWB + sg * 16;  // bytes

  // fragment-read lane geometry
  const int fr = lane & 15;   // M/N index within 16
  const int q = lane >> 4;    // quad -> k chunk of 32B
  const int swz = fr & 7;     // row&7 of the frag row

  // precomputed LDS frag base offsets (byte addresses)
  const int raRow = (wm * 64 + fr) * 128;
  const unsigned char* rbBase = ldsB + (wn * 64 + fr) * 128;
  const int off0 = (q ^ swz) * 16;        // slot holding granule 2q
  const int off1 = ((q + 4) ^ swz) * 16;  // slot holding granule 2q+1

  // ---- stage A once: wave w stages rows w*32..+31, all 4 K-chunks ----------
#pragma unroll
  for (int kk = 0; kk < 4; ++kk) {
    const unsigned char* gA = fQ + (size_t)(I0 + w * 32) * ROWB + kk * 128 + sOff;
    unsigned char* lA = ldsA[kk] + (w * 32) * 128;
#pragma unroll
    for (int rr = 0; rr < 32; rr += 8)
      load16_to_lds(gA + (size_t)rr * ROWB, lA + rr * 128);
  }
  // (first __syncthreads inside the kk loop below covers A readiness)

  float Zp[4][4];
#pragma unroll
  for (int m = 0; m < 4; ++m)
#pragma unroll
    for (int r = 0; r < 4; ++r) Zp[m][r] = 0.0f;

#pragma unroll 1
  for (int J = Jfirst; J < 64; J += 8) {
    const int J0 = J * 128;
    f32x4 acc[4][4];
#pragma unroll
    for (int m = 0; m < 4; ++m)
#pragma unroll
      for (int n = 0; n < 4; ++n) acc[m][n] = (f32x4){0.f, 0.f, 0.f, 0.f};

#pragma unroll 1
    for (int kk = 0; kk < 4; ++kk) {
      const int k0 = kk * 128;  // byte offset into row
      {  // B: 128 rows, wave stages rows w*32..+31 (4 instrs)
        const unsigned char* gB = fQ + (size_t)(J0 + w * 32) * ROWB + k0 + sOff;
        unsigned char* lB = ldsB + (w * 32) * 128;
#pragma unroll
        for (int rr = 0; rr < 32; rr += 8)
          load16_to_lds(gB + (size_t)rr * ROWB, lB + rr * 128);
      }
      __syncthreads();

      const unsigned char* raBase = ldsA[kk] + raRow;
      i32x8 bv[4];
#pragma unroll
      for (int n = 0; n < 4; ++n) {
        const unsigned char* rb = rbBase + n * 16 * 128;
        FragU u;
        u.h[0] = *(const int4*)(rb + off0);
        u.h[1] = *(const int4*)(rb + off1);
        bv[n] = u.v;
      }
#pragma unroll
      for (int mh = 0; mh < 2; ++mh) {  // m-split: av[2] live, not av[4]
        i32x8 av[2];
#pragma unroll
        for (int m = 0; m < 2; ++m) {
          const unsigned char* ra = raBase + (mh * 2 + m) * 16 * 128;
          FragU u;
          u.h[0] = *(const int4*)(ra + off0);
          u.h[1] = *(const int4*)(ra + off1);
          av[m] = u.v;
        }
#pragma unroll
        for (int m = 0; m < 2; ++m)
#pragma unroll
          for (int n = 0; n < 4; ++n)
            acc[mh * 2 + m][n] = __builtin_amdgcn_mfma_scale_f32_16x16x128_f8f6f4(
                av[m], bv[n], acc[mh * 2 + m][n], 0, 0, 0, 127, 0, 127);
      }
      __syncthreads();
    }

    // T01: sim[0,c], sim[1,c] from rows 0,1 (band I==0 only)
    if (I == 0 && wm == 0) {
      if (q == 0) {
#pragma unroll
        for (int n = 0; n < 4; ++n) {
          const int col = J0 + wn * 64 + n * 16 + fr;
          T01[col * 2 + 0] = acc[0][n][0] * INVT;
          T01[col * 2 + 1] = acc[0][n][1] * INVT;
        }
      }
    }

    // D: diagonal dots, from the diagonal tile only
    if (J == I) {
#pragma unroll
      for (int m = 0; m < 4; ++m)
#pragma unroll
        for (int n = 0; n < 4; ++n) {
          const int col = J0 + wn * 64 + n * 16 + fr;
#pragma unroll
          for (int r = 0; r < 4; ++r) {
            const int row = I0 + wm * 64 + m * 16 + q * 4 + r;
            if (row == col) D[row] = acc[m][n][r];
          }
        }
    }

    // Z: row partials always; column sums (transpose) for off-diag tiles
    const bool offd = (J != I);
#pragma unroll
    for (int n = 0; n < 4; ++n) {
      float cs = 0.0f;
#pragma unroll
      for (int m = 0; m < 4; ++m)
#pragma unroll
        for (int r = 0; r < 4; ++r) {
          const float e = FAST_EXP2((acc[m][n][r] - 1.0f) * SCALE_LOG2);
          Zp[m][r] += e;
          cs += e;
        }
      if (offd) {
        cs += __shfl_xor(cs, 16);
        cs += __shfl_xor(cs, 32);
        if (q == 0) atomicAdd(&Z[J0 + wn * 64 + n * 16 + fr], cs);
      }
    }
  }

  // row sums: reduce Zp across the 16 col-lanes, then atomicAdd
#pragma unroll
  for (int m = 0; m < 4; ++m)
#pragma unroll
    for (int r = 0; r < 4; ++r) {
      float v = Zp[m][r];
      v += __shfl_xor(v, 1);
      v += __shfl_xor(v, 2);
      v += __shfl_xor(v, 4);
      v += __shfl_xor(v, 8);
      if (fr == 0) atomicAdd(&Z[I0 + wm * 64 + m * 16 + q * 4 + r], v);
    }
}

// ---- K3: labels + exact-diagonal fixup + final loss reduction ---------------
// 1024 threads, 8 rows each, batched loads; raw v_log_f32 for ln(Zc).
__global__ __launch_bounds__(1024)
void finalize_kernel(const float* __restrict__ Z,
                     const float* __restrict__ T01,
                     const float* __restrict__ D,
                     const int* __restrict__ ids,
                     const int* __restrict__ anchor,
                     float* __restrict__ out) {
  __shared__ float red[1024];
  const int t = threadIdx.x;
  const int anchor_id = ids[anchor[0]];
  const int sameLast = (ids[B_N - 1] == anchor_id);
  const int samePrev = (ids[B_N - 2] == anchor_id);
  int i[8], id[8];
  float z[8], d[8], t0[8], t1[8];
#pragma unroll
  for (int u = 0; u < 8; ++u) {
    i[u] = u * 1024 + t;
    z[u] = Z[i[u]];
    d[u] = D[i[u]];
    t0[u] = T01[i[u] * 2 + 0];
    t1[u] = T01[i[u] * 2 + 1];
    id[u] = ids[i[u]];
  }
  float sum = 0.0f;
#pragma unroll
  for (int u = 0; u < 8; ++u) {
    const int same_i = (id[u] == anchor_id);
    const int lab =
        (i[u] < B_N - 1) ? (same_i & sameLast) : (sameLast & samePrev);
    const float tt = lab ? t1[u] : t0[u];
    // replace quantized diag contribution with the exact value exp(0)=1
    const float Zc = z[u] - FAST_EXP2((d[u] - 1.0f) * SCALE_LOG2) + 1.0f;
    sum += tt - (INVT + FAST_LN(Zc));
  }
  red[t] = sum;
  __syncthreads();
  for (int off = 512; off > 0; off >>= 1) {
    if (t < off) red[t] += red[t + off];
    __syncthreads();
  }
  if (t == 0) out[0] = -red[0] / (float)B_N;
}

// ---------------------------------------------------------------------------
extern "C" void kernel_launch(void* const* d_in, const int* in_sizes, int n_in,
                              void* d_out, int out_size, void* d_ws, size_t ws_size,
                              hipStream_t stream) {
  const float* x = (const float*)d_in[0];
  const int* ids = (const int*)d_in[1];
  const int* anchor = (const int*)d_in[2];
  float* out = (float*)d_out;

  unsigned char* fQ = (unsigned char*)d_ws;                    // 4 MB fp8
  float* Z = (float*)((char*)d_ws + (size_t)B_N * ROWB);       // 32 KB
  float* T01 = Z + B_N;                                        // 64 KB
  float* D = T01 + 2 * B_N;                                    // 32 KB

  norm_kernel<<<B_N / 8, 256, 0, stream>>>(x, fQ, Z);
  sim_kernel<<<dim3(32, 16), 256, 0, stream>>>(fQ, Z, T01, D);
  finalize_kernel<<<1, 1024, 0, stream>>>(Z, T01, D, ids, anchor, out);
}